// Round 18
// baseline (253.793 us; speedup 1.0000x reference)
//
#include <hip/hip_runtime.h>
#include <hip/hip_bf16.h>
#include <math.h>

#define B_ 4
#define S_ 2048
#define D_ 512
#define H_ 8
#define DK_ 64

typedef __bf16 bf16x8 __attribute__((ext_vector_type(8)));
typedef float f32x16 __attribute__((ext_vector_type(16)));
typedef float f32x4 __attribute__((ext_vector_type(4)));

static __device__ __forceinline__ unsigned short f2bf(float f) {
    unsigned int u = __builtin_bit_cast(unsigned int, f);
    unsigned int r = (u + 0x7FFFu + ((u >> 16) & 1u)) >> 16;
    return (unsigned short)r;
}

// ---- W_Q/W_K [H][D][DK] f32 -> [H][DK][D] bf16 ----
__global__ void k_transpose_w(const float* __restrict__ wq, const float* __restrict__ wk,
                              unsigned short* __restrict__ wqT, unsigned short* __restrict__ wkT) {
    int idx = blockIdx.x * blockDim.x + threadIdx.x;
    const int n = H_ * DK_ * D_;
    const float* src = idx < n ? wq : wk;
    unsigned short* dst = idx < n ? wqT : wkT;
    int o = idx < n ? idx : idx - n;
    int d  = o % D_;
    int hk = o / D_;
    int k  = hk % DK_;
    int h  = hk / DK_;
    dst[o] = f2bf(src[(h * D_ + d) * DK_ + k]);
}

// ---- decay table tab[h][n] = gamma_h^n ----
__global__ void k_decay(float* __restrict__ tab) {
    int i = blockIdx.x * blockDim.x + threadIdx.x;
    if (i >= H_ * S_) return;
    int h = i / S_;
    int n = i % S_;
    double xv = -3.4657359027997265 - (double)h * (2.772588722239781 / 7.0);
    double g = 1.0 - exp(xv);
    tab[i] = (float)pow(g, (double)n);
}

// ---- zero output 0 (16.8 MB, linear) ----
__global__ __launch_bounds__(256) void k_out0(float* __restrict__ out0) {
    f32x4* base = reinterpret_cast<f32x4*>(out0) + (size_t)blockIdx.x * 32768;
    f32x4 z = {0.f, 0.f, 0.f, 0.f};
#pragma unroll
    for (int j = 0; j < 128; ++j)
        base[threadIdx.x + j * 256] = z;
}

// ---- projection GEMM v2 (identical to round 12) ----
__global__ __launch_bounds__(256, 2) void k_proj(const float* __restrict__ x,
                                                 const unsigned short* __restrict__ wqT,
                                                 const unsigned short* __restrict__ wkT,
                                                 unsigned short* __restrict__ qb,
                                                 unsigned short* __restrict__ kb) {
    const int tid  = threadIdx.x;
    const int lane = tid & 63;
    const int wave = tid >> 6;
    const int m0   = blockIdx.x * 32;
    const int half = blockIdx.y;
    const unsigned short* wt = half ? wkT : wqT;
    unsigned short* outp     = half ? kb  : qb;

    __shared__ unsigned short atile[32 * 520];

    {
        const float4* xsrc = reinterpret_cast<const float4*>(x + (size_t)m0 * D_);
#pragma unroll
        for (int i = 0; i < 16; ++i) {
            int u   = tid + i * 256;
            int row = u >> 7, c4 = u & 127;
            float4 v = xsrc[u];
            ushort4 o;
            o.x = f2bf(v.x); o.y = f2bf(v.y); o.z = f2bf(v.z); o.w = f2bf(v.w);
            *reinterpret_cast<ushort4*>(&atile[row * 520 + c4 * 4]) = o;
        }
    }
    __syncthreads();

    const int row  = lane & 31;
    const int col  = lane & 31;
    const int hi   = lane >> 5;
    const int koff = hi * 8;
    const int n0   = wave * 128;

    const unsigned short* b0 = wt + (size_t)(n0 +  0 + row) * D_ + koff;
    const unsigned short* b1 = wt + (size_t)(n0 + 32 + row) * D_ + koff;
    const unsigned short* b2 = wt + (size_t)(n0 + 64 + row) * D_ + koff;
    const unsigned short* b3 = wt + (size_t)(n0 + 96 + row) * D_ + koff;
    const unsigned short* ap = atile + row * 520 + koff;

    f32x16 acc0 = {}, acc1 = {}, acc2 = {}, acc3 = {};
#pragma unroll
    for (int kk = 0; kk < D_; kk += 16) {
        bf16x8 a = *reinterpret_cast<const bf16x8*>(ap + kk);
        acc0 = __builtin_amdgcn_mfma_f32_32x32x16_bf16(a, *reinterpret_cast<const bf16x8*>(b0 + kk), acc0, 0, 0, 0);
        acc1 = __builtin_amdgcn_mfma_f32_32x32x16_bf16(a, *reinterpret_cast<const bf16x8*>(b1 + kk), acc1, 0, 0, 0);
        acc2 = __builtin_amdgcn_mfma_f32_32x32x16_bf16(a, *reinterpret_cast<const bf16x8*>(b2 + kk), acc2, 0, 0, 0);
        acc3 = __builtin_amdgcn_mfma_f32_32x32x16_bf16(a, *reinterpret_cast<const bf16x8*>(b3 + kk), acc3, 0, 0, 0);
    }

#define EPI(ACC, NB) { \
    int n = n0 + (NB) * 32 + col; \
    int hh = n >> 6, k = n & 63; \
    _Pragma("unroll") \
    for (int r = 0; r < 16; ++r) { \
        int rowD = (r & 3) + 8 * (r >> 2) + 4 * hi; \
        int m = m0 + rowD; \
        int bidx = m >> 11, s = m & 2047; \
        outp[(((size_t)bidx * H_ + hh) * S_ + s) * DK_ + k] = f2bf(ACC[r]); \
    } }
    EPI(acc0, 0) EPI(acc1, 1) EPI(acc2, 2) EPI(acc3, 3)
#undef EPI
}

// ---- unified A-writer: 8-row full-width slabs, fully LINEAR 64KB stores ----
// Grid (128, 32): block = slab pair (j, 255-j) of one bh; slab j = rows
// [8j,8j+8) x all 2048 cols = 64KB CONTIGUOUS memory (rows adjacent).
// 512 thr = 8 waves. Compute: 16x16x32 MFMA over the 16-row window
// containing the slab (half the C rows used); wave w does 16-col tiles
// t16 = w, w+8, ... < nt; factored decay; masked diagonal tile; results
// into [8][2048] LDS. Store: linear ascending 16B/thread stream over the
// whole slab, zeros synthesized for cols >= 16*nt. 64KB LDS -> 2 blocks/CU.
// Uniform work: 129 tiles/block. Barriers are lgkm-only (stores never drain
// in-loop).
__global__ __launch_bounds__(512) void k_slab(const unsigned short* __restrict__ qb,
                                              const unsigned short* __restrict__ kb,
                                              const float* __restrict__ tab,
                                              float* __restrict__ aout) {
    const int tid  = threadIdx.x;
    const int lane = tid & 63;
    const int wv   = tid >> 6;            // 0..7
    const int bx   = blockIdx.x;          // 0..127
    const int bh   = blockIdx.y;
    const int h    = bh & (H_ - 1);
    const float* th = tab + h * S_;
    float* ablk = aout + (size_t)bh * S_ * S_;

    __shared__ float lds[8 * 2048];       // 64KB

    const int l15  = lane & 15;           // A/B row within tile; C col
    const int lg   = lane >> 4;           // input k-group; C row-group
    const int koff = lg * 8;

    const float c1 = 1.0f / th[l15];
    float grc[4];
    int rowDv[4];
#pragma unroll
    for (int r = 0; r < 4; ++r) {
        rowDv[r] = lg * 4 + r;            // C row within 16-row window
        grc[r] = th[rowDv[r]] * c1;       // gamma^(rowD - col)
    }

    for (int half = 0; half < 2; ++half) {
        const int j    = half ? (255 - bx) : bx;
        const int w0   = j >> 1;          // 16-row window index
        const int s0w  = w0 << 4;         // window start row
        const int nt   = w0 + 1;          // 16-col tiles (incl. diagonal)
        const int jodd = j & 1;
        const bool mine = ((lane >> 5) == jodd);   // lanes holding this slab's rows
        const int rsub = jodd << 3;       // window-row -> slab-row offset

        // Q fragments for the window (shared by all waves)
        const unsigned short* qp = qb + ((size_t)bh * S_ + s0w + l15) * DK_ + koff;
        const bf16x8 qa0 = *reinterpret_cast<const bf16x8*>(qp);
        const bf16x8 qa1 = *reinterpret_cast<const bf16x8*>(qp + 32);

        for (int t16 = wv; t16 < nt; t16 += 8) {
            const unsigned short* kp = kb + ((size_t)bh * S_ + t16 * 16 + l15) * DK_ + koff;
            const bf16x8 kf0 = *reinterpret_cast<const bf16x8*>(kp);
            const bf16x8 kf1 = *reinterpret_cast<const bf16x8*>(kp + 32);
            f32x4 acc = {};
            acc = __builtin_amdgcn_mfma_f32_16x16x32_bf16(qa0, kf0, acc, 0, 0, 0);
            acc = __builtin_amdgcn_mfma_f32_16x16x32_bf16(qa1, kf1, acc, 0, 0, 0);
            if (mine) {
                float* lp = &lds[t16 * 16 + l15];
                if (t16 < w0) {
                    // full tile: d = 16*(w0-t16) + rowD - col >= 1
                    const float sc = th[(w0 - t16) << 4];
#pragma unroll
                    for (int r = 0; r < 4; ++r)
                        lp[(rowDv[r] - rsub) * 2048] = acc[r] * grc[r] * sc;
                } else {
                    // diagonal tile: d = rowD - col, masked
#pragma unroll
                    for (int r = 0; r < 4; ++r) {
                        int d = rowDv[r] - l15;
                        lp[(rowDv[r] - rsub) * 2048] = (d >= 0) ? acc[r] * th[d] : 0.0f;
                    }
                }
            }
        }
        // LDS writes visible (lgkm only — never drain global stores in-loop)
        asm volatile("s_waitcnt lgkmcnt(0)" ::: "memory");
        __builtin_amdgcn_sched_barrier(0);
        __builtin_amdgcn_s_barrier();

        // linear 64KB store: thread tid writes f32x4 at slab float-offset 4*(tid+i*512)
        float* base = ablk + (size_t)(j << 3) * S_;
        const int cl = nt << 4;           // computed-col limit (multiple of 16)
#pragma unroll
        for (int i = 0; i < 8; ++i) {
            const int f = (tid + i * 512) << 2;
            const int col = f & 2047;
            f32x4 v = {0.f, 0.f, 0.f, 0.f};
            if (col < cl) v = *reinterpret_cast<const f32x4*>(&lds[f]);
            *reinterpret_cast<f32x4*>(base + f) = v;
        }
        asm volatile("s_waitcnt lgkmcnt(0)" ::: "memory");
        __builtin_amdgcn_sched_barrier(0);
        __builtin_amdgcn_s_barrier();
    }
}

extern "C" void kernel_launch(void* const* d_in, const int* in_sizes, int n_in,
                              void* d_out, int out_size, void* d_ws, size_t ws_size,
                              hipStream_t stream) {
    const float* x  = (const float*)d_in[0];
    const float* wq = (const float*)d_in[1];
    const float* wk = (const float*)d_in[2];

    char* ws = (char*)d_ws;
    unsigned short* wqT = (unsigned short*)(ws);               //    524,288 B
    unsigned short* wkT = (unsigned short*)(ws + 524288);      //    524,288 B
    unsigned short* qb  = (unsigned short*)(ws + 1048576);     //  8,388,608 B
    unsigned short* kb  = (unsigned short*)(ws + 9437184);     //  8,388,608 B
    float*          tab = (float*)(ws + 17825792);             //     65,536 B

    float* out0 = (float*)d_out;
    float* aout = (float*)d_out + (size_t)B_ * S_ * D_;

    hipLaunchKernelGGL(k_transpose_w, dim3((2*H_*DK_*D_ + 255)/256), dim3(256), 0, stream,
                       wq, wk, wqT, wkT);
    hipLaunchKernelGGL(k_decay, dim3((H_*S_ + 255)/256), dim3(256), 0, stream, tab);
    hipLaunchKernelGGL(k_out0, dim3(32), dim3(256), 0, stream, out0);
    hipLaunchKernelGGL(k_proj, dim3(B_*S_/32, 2), dim3(256), 0, stream,
                       x, wqT, wkT, qb, kb);
    hipLaunchKernelGGL(k_slab, dim3(128, 32), dim3(512), 0, stream,
                       qb, kb, tab, aout);
}

// Round 19
// 178.343 us; speedup vs baseline: 1.4231x; 1.4231x over previous
//
#include <hip/hip_runtime.h>
#include <hip/hip_bf16.h>
#include <math.h>

#define B_ 4
#define S_ 2048
#define D_ 512
#define H_ 8
#define DK_ 64

typedef __bf16 bf16x8 __attribute__((ext_vector_type(8)));
typedef float f32x16 __attribute__((ext_vector_type(16)));
typedef float f32x4 __attribute__((ext_vector_type(4)));

static __device__ __forceinline__ unsigned short f2bf(float f) {
    unsigned int u = __builtin_bit_cast(unsigned int, f);
    unsigned int r = (u + 0x7FFFu + ((u >> 16) & 1u)) >> 16;
    return (unsigned short)r;
}

// ---- merged setup: W transpose (blocks 0..2047), decay table (2048..2111),
//      out0 zero (2112..2143) — one launch instead of three ----
__global__ __launch_bounds__(256) void k_setup(const float* __restrict__ wq, const float* __restrict__ wk,
                                               unsigned short* __restrict__ wqT, unsigned short* __restrict__ wkT,
                                               float* __restrict__ tab, float* __restrict__ out0) {
    const int bx = blockIdx.x;
    if (bx < 2048) {
        int idx = bx * 256 + threadIdx.x;
        const int n = H_ * DK_ * D_;
        const float* src = idx < n ? wq : wk;
        unsigned short* dst = idx < n ? wqT : wkT;
        int o = idx < n ? idx : idx - n;
        int d  = o % D_;
        int hk = o / D_;
        int k  = hk % DK_;
        int h  = hk / DK_;
        dst[o] = f2bf(src[(h * D_ + d) * DK_ + k]);
    } else if (bx < 2112) {
        int i = (bx - 2048) * 256 + threadIdx.x;
        if (i < H_ * S_) {
            int h = i / S_;
            int n = i % S_;
            double xv = -3.4657359027997265 - (double)h * (2.772588722239781 / 7.0);
            double g = 1.0 - exp(xv);
            tab[i] = (float)pow(g, (double)n);
        }
    } else {
        f32x4* base = reinterpret_cast<f32x4*>(out0) + (size_t)(bx - 2112) * 32768;
        f32x4 z = {0.f, 0.f, 0.f, 0.f};
#pragma unroll
        for (int j = 0; j < 128; ++j)
            base[threadIdx.x + j * 256] = z;
    }
}

// ---- zero-fill strictly-upper supertiles of A (identical body to R12) ----
// Runs LAST: pure stores, cannot pollute L2 for score's K/Q reads.
__global__ __launch_bounds__(256) void k_fill_upper(float* __restrict__ aout) {
    const int bh = blockIdx.y;
    f32x4 z = {0.f, 0.f, 0.f, 0.f};
    int r = blockIdx.x;
    int g = 0, cum = 0;
    for (; g < 7; ++g) { int cnt = 4 * (7 - g); if (r < cum + cnt) break; cum += cnt; }
    const int rr  = r - cum;
    const int per = 7 - g;
    const int panel = g * 4 + rr / per;
    const int st    = g + 1 + rr % per;

    float* base = aout + (size_t)bh * S_ * S_ + (size_t)(panel * 64) * S_ + st * 256;
    const int t = threadIdx.x;
#pragma unroll
    for (int j = 0; j < 16; ++j) {
        int u = t + j * 256;
        int row = u >> 6;
        int c4  = u & 63;
        *reinterpret_cast<f32x4*>(base + (size_t)row * S_ + c4 * 4) = z;
    }
}

// ---- projection GEMM v2: A-tile in LDS, convert fused (identical to R12) ----
__global__ __launch_bounds__(256, 2) void k_proj(const float* __restrict__ x,
                                                 const unsigned short* __restrict__ wqT,
                                                 const unsigned short* __restrict__ wkT,
                                                 unsigned short* __restrict__ qb,
                                                 unsigned short* __restrict__ kb) {
    const int tid  = threadIdx.x;
    const int lane = tid & 63;
    const int wave = tid >> 6;
    const int m0   = blockIdx.x * 32;
    const int half = blockIdx.y;
    const unsigned short* wt = half ? wkT : wqT;
    unsigned short* outp     = half ? kb  : qb;

    __shared__ unsigned short atile[32 * 520];

    {
        const float4* xsrc = reinterpret_cast<const float4*>(x + (size_t)m0 * D_);
#pragma unroll
        for (int i = 0; i < 16; ++i) {
            int u   = tid + i * 256;
            int row = u >> 7, c4 = u & 127;
            float4 v = xsrc[u];
            ushort4 o;
            o.x = f2bf(v.x); o.y = f2bf(v.y); o.z = f2bf(v.z); o.w = f2bf(v.w);
            *reinterpret_cast<ushort4*>(&atile[row * 520 + c4 * 4]) = o;
        }
    }
    __syncthreads();

    const int row  = lane & 31;
    const int col  = lane & 31;
    const int hi   = lane >> 5;
    const int koff = hi * 8;
    const int n0   = wave * 128;

    const unsigned short* b0 = wt + (size_t)(n0 +  0 + row) * D_ + koff;
    const unsigned short* b1 = wt + (size_t)(n0 + 32 + row) * D_ + koff;
    const unsigned short* b2 = wt + (size_t)(n0 + 64 + row) * D_ + koff;
    const unsigned short* b3 = wt + (size_t)(n0 + 96 + row) * D_ + koff;
    const unsigned short* ap = atile + row * 520 + koff;

    f32x16 acc0 = {}, acc1 = {}, acc2 = {}, acc3 = {};
#pragma unroll
    for (int kk = 0; kk < D_; kk += 16) {
        bf16x8 a = *reinterpret_cast<const bf16x8*>(ap + kk);
        acc0 = __builtin_amdgcn_mfma_f32_32x32x16_bf16(a, *reinterpret_cast<const bf16x8*>(b0 + kk), acc0, 0, 0, 0);
        acc1 = __builtin_amdgcn_mfma_f32_32x32x16_bf16(a, *reinterpret_cast<const bf16x8*>(b1 + kk), acc1, 0, 0, 0);
        acc2 = __builtin_amdgcn_mfma_f32_32x32x16_bf16(a, *reinterpret_cast<const bf16x8*>(b2 + kk), acc2, 0, 0, 0);
        acc3 = __builtin_amdgcn_mfma_f32_32x32x16_bf16(a, *reinterpret_cast<const bf16x8*>(b3 + kk), acc3, 0, 0, 0);
    }

#define EPI(ACC, NB) { \
    int n = n0 + (NB) * 32 + col; \
    int hh = n >> 6, k = n & 63; \
    _Pragma("unroll") \
    for (int r = 0; r < 16; ++r) { \
        int rowD = (r & 3) + 8 * (r >> 2) + 4 * hi; \
        int m = m0 + rowD; \
        int bidx = m >> 11, s = m & 2047; \
        outp[(((size_t)bidx * H_ + hh) * S_ + s) * DK_ + k] = f2bf(ACC[r]); \
    } }
    EPI(acc0, 0) EPI(acc1, 1) EPI(acc2, 2) EPI(acc3, 3)
#undef EPI
}

// ---- scores, lower-triangle only (identical body to R12) ----
// Runs RIGHT AFTER proj: qb/kb still L2-resident from proj's writes.
__global__ __launch_bounds__(256) void k_score(const unsigned short* __restrict__ qb,
                                               const unsigned short* __restrict__ kb,
                                               const float* __restrict__ tab,
                                               float* __restrict__ aout) {
    const int lane = threadIdx.x & 63;
    const int w    = threadIdx.x >> 6;
    const int id   = blockIdx.x;
    const int c    = id & 7, sidx = id >> 3;
    const int bh   = (c >> 1) + 4 * (sidx >> 3);
    const int p    = ((sidx & 7) << 1) | (c & 1);
    const int h    = bh & (H_ - 1);
    float* ablk = aout + (size_t)bh * S_ * S_;
    const float* th = tab + h * S_;

    __shared__ float tile[64 * 256];

    const int col  = lane & 31;
    const int hi   = lane >> 5;
    const int koff = hi * 8;

    const float c1 = 1.0f / th[col];
    float grc[16];
    int rowDv[16];
#pragma unroll
    for (int r = 0; r < 16; ++r) {
        rowDv[r] = (r & 3) + 8 * (r >> 2) + 4 * hi;
        grc[r] = th[rowDv[r]] * c1;
    }

    for (int pp = 0; pp < 2; ++pp) {
        const int panel = pp ? (31 - p) : p;
        const int s0 = panel * 64;
        const int qq = panel >> 2;
        const int rb = panel & 3;

        bf16x8 qf[2][4];
#pragma unroll
        for (int rg = 0; rg < 2; ++rg) {
            const unsigned short* qp = qb + ((size_t)bh * S_ + s0 + rg * 32 + col) * DK_ + koff;
#pragma unroll
            for (int i = 0; i < 4; ++i)
                qf[rg][i] = *reinterpret_cast<const bf16x8*>(qp + 16 * i);
        }

        for (int st = 0; st <= qq; ++st) {
            const int t0 = st * 256;
            const int ct0 = t0 + w * 64;
            const bool active = (st < qq) || (w <= rb);
            if (active) {
                f32x16 acc[2][2] = {{{}, {}}, {{}, {}}};
#pragma unroll
                for (int cg = 0; cg < 2; ++cg) {
                    const unsigned short* kp = kb + ((size_t)bh * S_ + ct0 + cg * 32 + col) * DK_ + koff;
                    bf16x8 kf0 = *reinterpret_cast<const bf16x8*>(kp);
                    bf16x8 kf1 = *reinterpret_cast<const bf16x8*>(kp + 16);
                    bf16x8 kf2 = *reinterpret_cast<const bf16x8*>(kp + 32);
                    bf16x8 kf3 = *reinterpret_cast<const bf16x8*>(kp + 48);
#pragma unroll
                    for (int rg = 0; rg < 2; ++rg) {
                        acc[rg][cg] = __builtin_amdgcn_mfma_f32_32x32x16_bf16(qf[rg][0], kf0, acc[rg][cg], 0, 0, 0);
                        acc[rg][cg] = __builtin_amdgcn_mfma_f32_32x32x16_bf16(qf[rg][1], kf1, acc[rg][cg], 0, 0, 0);
                        acc[rg][cg] = __builtin_amdgcn_mfma_f32_32x32x16_bf16(qf[rg][2], kf2, acc[rg][cg], 0, 0, 0);
                        acc[rg][cg] = __builtin_amdgcn_mfma_f32_32x32x16_bf16(qf[rg][3], kf3, acc[rg][cg], 0, 0, 0);
                    }
                }
                if (st < qq || w < rb) {
#pragma unroll
                    for (int rg = 0; rg < 2; ++rg) {
#pragma unroll
                        for (int cg = 0; cg < 2; ++cg) {
                            const float sc = th[s0 + rg * 32 - ct0 - cg * 32];
#pragma unroll
                            for (int r = 0; r < 16; ++r)
                                tile[(rg * 32 + rowDv[r]) * 256 + w * 64 + cg * 32 + col] =
                                    acc[rg][cg][r] * grc[r] * sc;
                        }
                    }
                } else {
#pragma unroll
                    for (int rg = 0; rg < 2; ++rg) {
#pragma unroll
                        for (int cg = 0; cg < 2; ++cg) {
                            const int dbase = 32 * (rg - cg);
#pragma unroll
                            for (int r = 0; r < 16; ++r) {
                                int d = dbase + rowDv[r] - col;
                                float v = (d >= 0) ? acc[rg][cg][r] * th[d] : 0.0f;
                                tile[(rg * 32 + rowDv[r]) * 256 + w * 64 + cg * 32 + col] = v;
                            }
                        }
                    }
                }
            } else {
                f32x4 z = {0.f, 0.f, 0.f, 0.f};
#pragma unroll
                for (int i = 0; i < 16; ++i) {
                    int r = i * 4 + (lane >> 4);
                    int cc = (lane & 15) * 4;
                    *reinterpret_cast<f32x4*>(&tile[r * 256 + w * 64 + cc]) = z;
                }
            }
            __syncthreads();
#pragma unroll
            for (int r = 0; r < 16; ++r) {
                int row = w * 16 + r;
                f32x4 v = *reinterpret_cast<const f32x4*>(&tile[row * 256 + lane * 4]);
                *reinterpret_cast<f32x4*>(ablk + (size_t)(s0 + row) * S_ + t0 + lane * 4) = v;
            }
            __syncthreads();
        }
    }
}

extern "C" void kernel_launch(void* const* d_in, const int* in_sizes, int n_in,
                              void* d_out, int out_size, void* d_ws, size_t ws_size,
                              hipStream_t stream) {
    const float* x  = (const float*)d_in[0];
    const float* wq = (const float*)d_in[1];
    const float* wk = (const float*)d_in[2];

    char* ws = (char*)d_ws;
    unsigned short* wqT = (unsigned short*)(ws);               //    524,288 B
    unsigned short* wkT = (unsigned short*)(ws + 524288);      //    524,288 B
    unsigned short* qb  = (unsigned short*)(ws + 1048576);     //  8,388,608 B
    unsigned short* kb  = (unsigned short*)(ws + 9437184);     //  8,388,608 B
    float*          tab = (float*)(ws + 17825792);             //     65,536 B

    float* out0 = (float*)d_out;
    float* aout = (float*)d_out + (size_t)B_ * S_ * D_;

    // Order: setup -> proj -> score (L2-warm Q/K) -> fill (pure stores, last)
    hipLaunchKernelGGL(k_setup, dim3(2144), dim3(256), 0, stream,
                       wq, wk, wqT, wkT, tab, out0);
    hipLaunchKernelGGL(k_proj, dim3(B_*S_/32, 2), dim3(256), 0, stream,
                       x, wqT, wkT, qb, kb);
    hipLaunchKernelGGL(k_score, dim3(512), dim3(256), 0, stream,
                       qb, kb, tab, aout);
    hipLaunchKernelGGL(k_fill_upper, dim3(112, 32), dim3(256), 0, stream, aout);
}

// Round 20
// 166.763 us; speedup vs baseline: 1.5219x; 1.0694x over previous
//
#include <hip/hip_runtime.h>
#include <hip/hip_bf16.h>
#include <math.h>

#define B_ 4
#define S_ 2048
#define D_ 512
#define H_ 8
#define DK_ 64

typedef __bf16 bf16x8 __attribute__((ext_vector_type(8)));
typedef float f32x16 __attribute__((ext_vector_type(16)));
typedef float f32x4 __attribute__((ext_vector_type(4)));

static __device__ __forceinline__ unsigned short f2bf(float f) {
    unsigned int u = __builtin_bit_cast(unsigned int, f);
    unsigned int r = (u + 0x7FFFu + ((u >> 16) & 1u)) >> 16;
    return (unsigned short)r;
}

// ---- merged setup: W transpose (blocks 0..2047), decay table (2048..2111) ----
__global__ __launch_bounds__(256) void k_setup(const float* __restrict__ wq, const float* __restrict__ wk,
                                               unsigned short* __restrict__ wqT, unsigned short* __restrict__ wkT,
                                               float* __restrict__ tab) {
    const int bx = blockIdx.x;
    if (bx < 2048) {
        int idx = bx * 256 + threadIdx.x;
        const int n = H_ * DK_ * D_;
        const float* src = idx < n ? wq : wk;
        unsigned short* dst = idx < n ? wqT : wkT;
        int o = idx < n ? idx : idx - n;
        int d  = o % D_;
        int hk = o / D_;
        int k  = hk % DK_;
        int h  = hk / DK_;
        dst[o] = f2bf(src[(h * D_ + d) * DK_ + k]);
    } else {
        int i = (bx - 2048) * 256 + threadIdx.x;
        if (i < H_ * S_) {
            int h = i / S_;
            int n = i % S_;
            double xv = -3.4657359027997265 - (double)h * (2.772588722239781 / 7.0);
            double g = 1.0 - exp(xv);
            tab[i] = (float)pow(g, (double)n);
        }
    }
}

// ---- projection GEMM v2 (identical to R12) ----
__global__ __launch_bounds__(256, 2) void k_proj(const float* __restrict__ x,
                                                 const unsigned short* __restrict__ wqT,
                                                 const unsigned short* __restrict__ wkT,
                                                 unsigned short* __restrict__ qb,
                                                 unsigned short* __restrict__ kb) {
    const int tid  = threadIdx.x;
    const int lane = tid & 63;
    const int wave = tid >> 6;
    const int m0   = blockIdx.x * 32;
    const int half = blockIdx.y;
    const unsigned short* wt = half ? wkT : wqT;
    unsigned short* outp     = half ? kb  : qb;

    __shared__ unsigned short atile[32 * 520];

    {
        const float4* xsrc = reinterpret_cast<const float4*>(x + (size_t)m0 * D_);
#pragma unroll
        for (int i = 0; i < 16; ++i) {
            int u   = tid + i * 256;
            int row = u >> 7, c4 = u & 127;
            float4 v = xsrc[u];
            ushort4 o;
            o.x = f2bf(v.x); o.y = f2bf(v.y); o.z = f2bf(v.z); o.w = f2bf(v.w);
            *reinterpret_cast<ushort4*>(&atile[row * 520 + c4 * 4]) = o;
        }
    }
    __syncthreads();

    const int row  = lane & 31;
    const int col  = lane & 31;
    const int hi   = lane >> 5;
    const int koff = hi * 8;
    const int n0   = wave * 128;

    const unsigned short* b0 = wt + (size_t)(n0 +  0 + row) * D_ + koff;
    const unsigned short* b1 = wt + (size_t)(n0 + 32 + row) * D_ + koff;
    const unsigned short* b2 = wt + (size_t)(n0 + 64 + row) * D_ + koff;
    const unsigned short* b3 = wt + (size_t)(n0 + 96 + row) * D_ + koff;
    const unsigned short* ap = atile + row * 520 + koff;

    f32x16 acc0 = {}, acc1 = {}, acc2 = {}, acc3 = {};
#pragma unroll
    for (int kk = 0; kk < D_; kk += 16) {
        bf16x8 a = *reinterpret_cast<const bf16x8*>(ap + kk);
        acc0 = __builtin_amdgcn_mfma_f32_32x32x16_bf16(a, *reinterpret_cast<const bf16x8*>(b0 + kk), acc0, 0, 0, 0);
        acc1 = __builtin_amdgcn_mfma_f32_32x32x16_bf16(a, *reinterpret_cast<const bf16x8*>(b1 + kk), acc1, 0, 0, 0);
        acc2 = __builtin_amdgcn_mfma_f32_32x32x16_bf16(a, *reinterpret_cast<const bf16x8*>(b2 + kk), acc2, 0, 0, 0);
        acc3 = __builtin_amdgcn_mfma_f32_32x32x16_bf16(a, *reinterpret_cast<const bf16x8*>(b3 + kk), acc3, 0, 0, 0);
    }

#define EPI(ACC, NB) { \
    int n = n0 + (NB) * 32 + col; \
    int hh = n >> 6, k = n & 63; \
    _Pragma("unroll") \
    for (int r = 0; r < 16; ++r) { \
        int rowD = (r & 3) + 8 * (r >> 2) + 4 * hi; \
        int m = m0 + rowD; \
        int bidx = m >> 11, s = m & 2047; \
        outp[(((size_t)bidx * H_ + hh) * S_ + s) * DK_ + k] = f2bf(ACC[r]); \
    } }
    EPI(acc0, 0) EPI(acc1, 1) EPI(acc2, 2) EPI(acc3, 3)
#undef EPI
}

// ---- score part: R12/R19 body, LDS passed in ----
static __device__ __forceinline__ void score_part(int id, int tid,
        const unsigned short* __restrict__ qb, const unsigned short* __restrict__ kb,
        const float* __restrict__ tab, float* __restrict__ aout, float* tile) {
    const int lane = tid & 63;
    const int w    = tid >> 6;
    const int c    = id & 7, sidx = id >> 3;
    const int bh   = (c >> 1) + 4 * (sidx >> 3);
    const int p    = ((sidx & 7) << 1) | (c & 1);
    const int h    = bh & (H_ - 1);
    float* ablk = aout + (size_t)bh * S_ * S_;
    const float* th = tab + h * S_;

    const int col  = lane & 31;
    const int hi   = lane >> 5;
    const int koff = hi * 8;

    const float c1 = 1.0f / th[col];
    float grc[16];
    int rowDv[16];
#pragma unroll
    for (int r = 0; r < 16; ++r) {
        rowDv[r] = (r & 3) + 8 * (r >> 2) + 4 * hi;
        grc[r] = th[rowDv[r]] * c1;
    }

    for (int pp = 0; pp < 2; ++pp) {
        const int panel = pp ? (31 - p) : p;
        const int s0 = panel * 64;
        const int qq = panel >> 2;
        const int rb = panel & 3;

        bf16x8 qf[2][4];
#pragma unroll
        for (int rg = 0; rg < 2; ++rg) {
            const unsigned short* qp = qb + ((size_t)bh * S_ + s0 + rg * 32 + col) * DK_ + koff;
#pragma unroll
            for (int i = 0; i < 4; ++i)
                qf[rg][i] = *reinterpret_cast<const bf16x8*>(qp + 16 * i);
        }

        for (int st = 0; st <= qq; ++st) {
            const int t0 = st * 256;
            const int ct0 = t0 + w * 64;
            const bool active = (st < qq) || (w <= rb);
            if (active) {
                f32x16 acc[2][2] = {{{}, {}}, {{}, {}}};
#pragma unroll
                for (int cg = 0; cg < 2; ++cg) {
                    const unsigned short* kp = kb + ((size_t)bh * S_ + ct0 + cg * 32 + col) * DK_ + koff;
                    bf16x8 kf0 = *reinterpret_cast<const bf16x8*>(kp);
                    bf16x8 kf1 = *reinterpret_cast<const bf16x8*>(kp + 16);
                    bf16x8 kf2 = *reinterpret_cast<const bf16x8*>(kp + 32);
                    bf16x8 kf3 = *reinterpret_cast<const bf16x8*>(kp + 48);
#pragma unroll
                    for (int rg = 0; rg < 2; ++rg) {
                        acc[rg][cg] = __builtin_amdgcn_mfma_f32_32x32x16_bf16(qf[rg][0], kf0, acc[rg][cg], 0, 0, 0);
                        acc[rg][cg] = __builtin_amdgcn_mfma_f32_32x32x16_bf16(qf[rg][1], kf1, acc[rg][cg], 0, 0, 0);
                        acc[rg][cg] = __builtin_amdgcn_mfma_f32_32x32x16_bf16(qf[rg][2], kf2, acc[rg][cg], 0, 0, 0);
                        acc[rg][cg] = __builtin_amdgcn_mfma_f32_32x32x16_bf16(qf[rg][3], kf3, acc[rg][cg], 0, 0, 0);
                    }
                }
                if (st < qq || w < rb) {
#pragma unroll
                    for (int rg = 0; rg < 2; ++rg) {
#pragma unroll
                        for (int cg = 0; cg < 2; ++cg) {
                            const float sc = th[s0 + rg * 32 - ct0 - cg * 32];
#pragma unroll
                            for (int r = 0; r < 16; ++r)
                                tile[(rg * 32 + rowDv[r]) * 256 + w * 64 + cg * 32 + col] =
                                    acc[rg][cg][r] * grc[r] * sc;
                        }
                    }
                } else {
#pragma unroll
                    for (int rg = 0; rg < 2; ++rg) {
#pragma unroll
                        for (int cg = 0; cg < 2; ++cg) {
                            const int dbase = 32 * (rg - cg);
#pragma unroll
                            for (int r = 0; r < 16; ++r) {
                                int d = dbase + rowDv[r] - col;
                                float v = (d >= 0) ? acc[rg][cg][r] * th[d] : 0.0f;
                                tile[(rg * 32 + rowDv[r]) * 256 + w * 64 + cg * 32 + col] = v;
                            }
                        }
                    }
                }
            } else {
                f32x4 z = {0.f, 0.f, 0.f, 0.f};
#pragma unroll
                for (int i = 0; i < 16; ++i) {
                    int r = i * 4 + (lane >> 4);
                    int cc = (lane & 15) * 4;
                    *reinterpret_cast<f32x4*>(&tile[r * 256 + w * 64 + cc]) = z;
                }
            }
            __syncthreads();
#pragma unroll
            for (int r = 0; r < 16; ++r) {
                int row = w * 16 + r;
                f32x4 v = *reinterpret_cast<const f32x4*>(&tile[row * 256 + lane * 4]);
                *reinterpret_cast<f32x4*>(ablk + (size_t)(s0 + row) * S_ + t0 + lane * 4) = v;
            }
            __syncthreads();
        }
    }
}

// ---- fill part: 7 upper supertiles + one 32KB out0 chunk per block ----
static __device__ __forceinline__ void fill_part(int bid, int tid,
        float* __restrict__ aout, float* __restrict__ out0) {
    f32x4 z = {0.f, 0.f, 0.f, 0.f};
#pragma unroll 1
    for (int i = 0; i < 7; ++i) {
        const int f = bid * 7 + i;            // 0..3583
        const int bh = f / 112;
        int r = f % 112;
        int g = 0, cum = 0;
        for (; g < 7; ++g) { int cnt = 4 * (7 - g); if (r < cum + cnt) break; cum += cnt; }
        const int rr  = r - cum;
        const int per = 7 - g;
        const int panel = g * 4 + rr / per;
        const int st    = g + 1 + rr % per;
        float* base = aout + (size_t)bh * S_ * S_ + (size_t)(panel * 64) * S_ + st * 256;
#pragma unroll
        for (int j = 0; j < 16; ++j) {
            int u = tid + j * 256;
            int row = u >> 6;
            int c4  = u & 63;
            *reinterpret_cast<f32x4*>(base + (size_t)row * S_ + c4 * 4) = z;
        }
    }
    // out0 chunk: 2048 f32x4 per block
    f32x4* b0 = reinterpret_cast<f32x4*>(out0) + (size_t)bid * 2048;
#pragma unroll
    for (int j = 0; j < 8; ++j)
        b0[tid + j * 256] = z;
}

// ---- merged score+fill: even blocks score->fill, odd blocks fill->score ----
// At any instant ~half the resident blocks are pure-store streams soaking up
// the write-pipe bubbles left by the compute-phase blocks, then they swap.
__global__ __launch_bounds__(256) void k_scorefill(const unsigned short* __restrict__ qb,
                                                   const unsigned short* __restrict__ kb,
                                                   const float* __restrict__ tab,
                                                   float* __restrict__ aout,
                                                   float* __restrict__ out0) {
    __shared__ __align__(16) float tile[64 * 256];   // 64KB
    const int bid = blockIdx.x;
    const int tid = threadIdx.x;
    if (bid & 1) {
        fill_part(bid, tid, aout, out0);
        score_part(bid, tid, qb, kb, tab, aout, tile);
    } else {
        score_part(bid, tid, qb, kb, tab, aout, tile);
        fill_part(bid, tid, aout, out0);
    }
}

extern "C" void kernel_launch(void* const* d_in, const int* in_sizes, int n_in,
                              void* d_out, int out_size, void* d_ws, size_t ws_size,
                              hipStream_t stream) {
    const float* x  = (const float*)d_in[0];
    const float* wq = (const float*)d_in[1];
    const float* wk = (const float*)d_in[2];

    char* ws = (char*)d_ws;
    unsigned short* wqT = (unsigned short*)(ws);               //    524,288 B
    unsigned short* wkT = (unsigned short*)(ws + 524288);      //    524,288 B
    unsigned short* qb  = (unsigned short*)(ws + 1048576);     //  8,388,608 B
    unsigned short* kb  = (unsigned short*)(ws + 9437184);     //  8,388,608 B
    float*          tab = (float*)(ws + 17825792);             //     65,536 B

    float* out0 = (float*)d_out;
    float* aout = (float*)d_out + (size_t)B_ * S_ * D_;

    hipLaunchKernelGGL(k_setup, dim3(2112), dim3(256), 0, stream,
                       wq, wk, wqT, wkT, tab);
    hipLaunchKernelGGL(k_proj, dim3(B_*S_/32, 2), dim3(256), 0, stream,
                       x, wqT, wkT, qb, kb);
    hipLaunchKernelGGL(k_scorefill, dim3(512), dim3(256), 0, stream,
                       qb, kb, tab, aout, out0);
}

// Round 21
// 165.338 us; speedup vs baseline: 1.5350x; 1.0086x over previous
//
#include <hip/hip_runtime.h>
#include <hip/hip_bf16.h>
#include <math.h>

#define B_ 4
#define S_ 2048
#define D_ 512
#define H_ 8
#define DK_ 64

typedef __bf16 bf16x8 __attribute__((ext_vector_type(8)));
typedef float f32x16 __attribute__((ext_vector_type(16)));
typedef float f32x4 __attribute__((ext_vector_type(4)));

static __device__ __forceinline__ unsigned short f2bf(float f) {
    unsigned int u = __builtin_bit_cast(unsigned int, f);
    unsigned int r = (u + 0x7FFFu + ((u >> 16) & 1u)) >> 16;
    return (unsigned short)r;
}

// ---- merged setup: W transpose (blocks 0..2047), decay table (2048..2111) ----
__global__ __launch_bounds__(256) void k_setup(const float* __restrict__ wq, const float* __restrict__ wk,
                                               unsigned short* __restrict__ wqT, unsigned short* __restrict__ wkT,
                                               float* __restrict__ tab) {
    const int bx = blockIdx.x;
    if (bx < 2048) {
        int idx = bx * 256 + threadIdx.x;
        const int n = H_ * DK_ * D_;
        const float* src = idx < n ? wq : wk;
        unsigned short* dst = idx < n ? wqT : wkT;
        int o = idx < n ? idx : idx - n;
        int d  = o % D_;
        int hk = o / D_;
        int k  = hk % DK_;
        int h  = hk / DK_;
        dst[o] = f2bf(src[(h * D_ + d) * DK_ + k]);
    } else {
        int i = (bx - 2048) * 256 + threadIdx.x;
        if (i < H_ * S_) {
            int h = i / S_;
            int n = i % S_;
            double xv = -3.4657359027997265 - (double)h * (2.772588722239781 / 7.0);
            double g = 1.0 - exp(xv);
            tab[i] = (float)pow(g, (double)n);
        }
    }
}

// ---- projection GEMM v2 (identical to R12) ----
__global__ __launch_bounds__(256, 2) void k_proj(const float* __restrict__ x,
                                                 const unsigned short* __restrict__ wqT,
                                                 const unsigned short* __restrict__ wkT,
                                                 unsigned short* __restrict__ qb,
                                                 unsigned short* __restrict__ kb) {
    const int tid  = threadIdx.x;
    const int lane = tid & 63;
    const int wave = tid >> 6;
    const int m0   = blockIdx.x * 32;
    const int half = blockIdx.y;
    const unsigned short* wt = half ? wkT : wqT;
    unsigned short* outp     = half ? kb  : qb;

    __shared__ unsigned short atile[32 * 520];

    {
        const float4* xsrc = reinterpret_cast<const float4*>(x + (size_t)m0 * D_);
#pragma unroll
        for (int i = 0; i < 16; ++i) {
            int u   = tid + i * 256;
            int row = u >> 7, c4 = u & 127;
            float4 v = xsrc[u];
            ushort4 o;
            o.x = f2bf(v.x); o.y = f2bf(v.y); o.z = f2bf(v.z); o.w = f2bf(v.w);
            *reinterpret_cast<ushort4*>(&atile[row * 520 + c4 * 4]) = o;
        }
    }
    __syncthreads();

    const int row  = lane & 31;
    const int col  = lane & 31;
    const int hi   = lane >> 5;
    const int koff = hi * 8;
    const int n0   = wave * 128;

    const unsigned short* b0 = wt + (size_t)(n0 +  0 + row) * D_ + koff;
    const unsigned short* b1 = wt + (size_t)(n0 + 32 + row) * D_ + koff;
    const unsigned short* b2 = wt + (size_t)(n0 + 64 + row) * D_ + koff;
    const unsigned short* b3 = wt + (size_t)(n0 + 96 + row) * D_ + koff;
    const unsigned short* ap = atile + row * 520 + koff;

    f32x16 acc0 = {}, acc1 = {}, acc2 = {}, acc3 = {};
#pragma unroll
    for (int kk = 0; kk < D_; kk += 16) {
        bf16x8 a = *reinterpret_cast<const bf16x8*>(ap + kk);
        acc0 = __builtin_amdgcn_mfma_f32_32x32x16_bf16(a, *reinterpret_cast<const bf16x8*>(b0 + kk), acc0, 0, 0, 0);
        acc1 = __builtin_amdgcn_mfma_f32_32x32x16_bf16(a, *reinterpret_cast<const bf16x8*>(b1 + kk), acc1, 0, 0, 0);
        acc2 = __builtin_amdgcn_mfma_f32_32x32x16_bf16(a, *reinterpret_cast<const bf16x8*>(b2 + kk), acc2, 0, 0, 0);
        acc3 = __builtin_amdgcn_mfma_f32_32x32x16_bf16(a, *reinterpret_cast<const bf16x8*>(b3 + kk), acc3, 0, 0, 0);
    }

#define EPI(ACC, NB) { \
    int n = n0 + (NB) * 32 + col; \
    int hh = n >> 6, k = n & 63; \
    _Pragma("unroll") \
    for (int r = 0; r < 16; ++r) { \
        int rowD = (r & 3) + 8 * (r >> 2) + 4 * hi; \
        int m = m0 + rowD; \
        int bidx = m >> 11, s = m & 2047; \
        outp[(((size_t)bidx * H_ + hh) * S_ + s) * DK_ + k] = f2bf(ACC[r]); \
    } }
    EPI(acc0, 0) EPI(acc1, 1) EPI(acc2, 2) EPI(acc3, 3)
#undef EPI
}

// ---- one fill unit: i<7 -> one upper-zero 64x256 supertile; i==7 -> out0 chunk ----
static __device__ __forceinline__ void fill_step(int bid, int i, int tid,
        float* __restrict__ aout, float* __restrict__ out0) {
    f32x4 z = {0.f, 0.f, 0.f, 0.f};
    if (i < 7) {
        const int f = bid * 7 + i;            // 0..3583
        const int bh = f / 112;
        int r = f % 112;
        int g = 0, cum = 0;
        for (; g < 7; ++g) { int cnt = 4 * (7 - g); if (r < cum + cnt) break; cum += cnt; }
        const int rr  = r - cum;
        const int per = 7 - g;
        const int panel = g * 4 + rr / per;
        const int st    = g + 1 + rr % per;
        float* base = aout + (size_t)bh * S_ * S_ + (size_t)(panel * 64) * S_ + st * 256;
#pragma unroll
        for (int j = 0; j < 16; ++j) {
            int u = tid + j * 256;
            *reinterpret_cast<f32x4*>(base + (size_t)(u >> 6) * S_ + (u & 63) * 4) = z;
        }
    } else {
        f32x4* b0 = reinterpret_cast<f32x4*>(out0) + (size_t)bid * 2048;
#pragma unroll
        for (int j = 0; j < 8; ++j)
            b0[tid + j * 256] = z;
    }
}

// ---- merged score+fill, supertile-level interleave ----
// One fill unit is issued at the TOP of each score-supertile iteration: its
// zero stores enter the VMEM queue before the K-load/MFMA/epilogue phase and
// drain during it (the store-pipe bubble). 9 score STs >= 8 fill units.
__global__ __launch_bounds__(256) void k_scorefill(const unsigned short* __restrict__ qb,
                                                   const unsigned short* __restrict__ kb,
                                                   const float* __restrict__ tab,
                                                   float* __restrict__ aout,
                                                   float* __restrict__ out0) {
    __shared__ __align__(16) float tile[64 * 256];   // 64KB
    const int id  = blockIdx.x;
    const int tid = threadIdx.x;
    const int lane = tid & 63;
    const int w    = tid >> 6;
    const int c    = id & 7, sidx = id >> 3;
    const int bh   = (c >> 1) + 4 * (sidx >> 3);
    const int p    = ((sidx & 7) << 1) | (c & 1);
    const int h    = bh & (H_ - 1);
    float* ablk = aout + (size_t)bh * S_ * S_;
    const float* th = tab + h * S_;

    const int col  = lane & 31;
    const int hi   = lane >> 5;
    const int koff = hi * 8;

    const float c1 = 1.0f / th[col];
    float grc[16];
    int rowDv[16];
#pragma unroll
    for (int r = 0; r < 16; ++r) {
        rowDv[r] = (r & 3) + 8 * (r >> 2) + 4 * hi;
        grc[r] = th[rowDv[r]] * c1;
    }

    int fillIdx = 0;

    for (int pp = 0; pp < 2; ++pp) {
        const int panel = pp ? (31 - p) : p;
        const int s0 = panel * 64;
        const int qq = panel >> 2;
        const int rb = panel & 3;

        bf16x8 qf[2][4];
#pragma unroll
        for (int rg = 0; rg < 2; ++rg) {
            const unsigned short* qp = qb + ((size_t)bh * S_ + s0 + rg * 32 + col) * DK_ + koff;
#pragma unroll
            for (int i = 0; i < 4; ++i)
                qf[rg][i] = *reinterpret_cast<const bf16x8*>(qp + 16 * i);
        }

        for (int st = 0; st <= qq; ++st) {
            // interleaved fill unit: stores drain during the compute below
            if (fillIdx < 8) { fill_step(id, fillIdx, tid, aout, out0); ++fillIdx; }

            const int t0 = st * 256;
            const int ct0 = t0 + w * 64;
            const bool active = (st < qq) || (w <= rb);
            if (active) {
                f32x16 acc[2][2] = {{{}, {}}, {{}, {}}};
#pragma unroll
                for (int cg = 0; cg < 2; ++cg) {
                    const unsigned short* kp = kb + ((size_t)bh * S_ + ct0 + cg * 32 + col) * DK_ + koff;
                    bf16x8 kf0 = *reinterpret_cast<const bf16x8*>(kp);
                    bf16x8 kf1 = *reinterpret_cast<const bf16x8*>(kp + 16);
                    bf16x8 kf2 = *reinterpret_cast<const bf16x8*>(kp + 32);
                    bf16x8 kf3 = *reinterpret_cast<const bf16x8*>(kp + 48);
#pragma unroll
                    for (int rg = 0; rg < 2; ++rg) {
                        acc[rg][cg] = __builtin_amdgcn_mfma_f32_32x32x16_bf16(qf[rg][0], kf0, acc[rg][cg], 0, 0, 0);
                        acc[rg][cg] = __builtin_amdgcn_mfma_f32_32x32x16_bf16(qf[rg][1], kf1, acc[rg][cg], 0, 0, 0);
                        acc[rg][cg] = __builtin_amdgcn_mfma_f32_32x32x16_bf16(qf[rg][2], kf2, acc[rg][cg], 0, 0, 0);
                        acc[rg][cg] = __builtin_amdgcn_mfma_f32_32x32x16_bf16(qf[rg][3], kf3, acc[rg][cg], 0, 0, 0);
                    }
                }
                if (st < qq || w < rb) {
#pragma unroll
                    for (int rg = 0; rg < 2; ++rg) {
#pragma unroll
                        for (int cg = 0; cg < 2; ++cg) {
                            const float sc = th[s0 + rg * 32 - ct0 - cg * 32];
#pragma unroll
                            for (int r = 0; r < 16; ++r)
                                tile[(rg * 32 + rowDv[r]) * 256 + w * 64 + cg * 32 + col] =
                                    acc[rg][cg][r] * grc[r] * sc;
                        }
                    }
                } else {
#pragma unroll
                    for (int rg = 0; rg < 2; ++rg) {
#pragma unroll
                        for (int cg = 0; cg < 2; ++cg) {
                            const int dbase = 32 * (rg - cg);
#pragma unroll
                            for (int r = 0; r < 16; ++r) {
                                int d = dbase + rowDv[r] - col;
                                float v = (d >= 0) ? acc[rg][cg][r] * th[d] : 0.0f;
                                tile[(rg * 32 + rowDv[r]) * 256 + w * 64 + cg * 32 + col] = v;
                            }
                        }
                    }
                }
            } else {
                f32x4 z = {0.f, 0.f, 0.f, 0.f};
#pragma unroll
                for (int i = 0; i < 16; ++i) {
                    int r = i * 4 + (lane >> 4);
                    int cc = (lane & 15) * 4;
                    *reinterpret_cast<f32x4*>(&tile[r * 256 + w * 64 + cc]) = z;
                }
            }
            __syncthreads();
#pragma unroll
            for (int r = 0; r < 16; ++r) {
                int row = w * 16 + r;
                f32x4 v = *reinterpret_cast<const f32x4*>(&tile[row * 256 + lane * 4]);
                *reinterpret_cast<f32x4*>(ablk + (size_t)(s0 + row) * S_ + t0 + lane * 4) = v;
            }
            __syncthreads();
        }
    }
}

extern "C" void kernel_launch(void* const* d_in, const int* in_sizes, int n_in,
                              void* d_out, int out_size, void* d_ws, size_t ws_size,
                              hipStream_t stream) {
    const float* x  = (const float*)d_in[0];
    const float* wq = (const float*)d_in[1];
    const float* wk = (const float*)d_in[2];

    char* ws = (char*)d_ws;
    unsigned short* wqT = (unsigned short*)(ws);               //    524,288 B
    unsigned short* wkT = (unsigned short*)(ws + 524288);      //    524,288 B
    unsigned short* qb  = (unsigned short*)(ws + 1048576);     //  8,388,608 B
    unsigned short* kb  = (unsigned short*)(ws + 9437184);     //  8,388,608 B
    float*          tab = (float*)(ws + 17825792);             //     65,536 B

    float* out0 = (float*)d_out;
    float* aout = (float*)d_out + (size_t)B_ * S_ * D_;

    hipLaunchKernelGGL(k_setup, dim3(2112), dim3(256), 0, stream,
                       wq, wk, wqT, wkT, tab);
    hipLaunchKernelGGL(k_proj, dim3(B_*S_/32, 2), dim3(256), 0, stream,
                       x, wqT, wkT, qb, kb);
    hipLaunchKernelGGL(k_scorefill, dim3(512), dim3(256), 0, stream,
                       qb, kb, tab, aout, out0);
}